// Round 5
// baseline (11565.150 us; speedup 1.0000x reference)
//
#include <hip/hip_runtime.h>

typedef float f32x4 __attribute__((ext_vector_type(4)));

namespace {
constexpr int Bn = 64, Sn = 512, Fn = 128, Hn = 512;
constexpr int NWG = 256, NTHR = 256;
constexpr int HXS = 644;    // hx row stride (dwords), 16B-aligned
constexpr int PQS = 581;    // part q-plane stride (dwords): 581%32=5 -> 2-way banks
constexpr int RING0 = 1024; // ring base offset in floats (first 4 KB = barrier counters)
}

__device__ __forceinline__ float sigmoid_f(float v) {
    return 1.0f / (1.0f + __expf(-v));
}
__device__ __forceinline__ float tanh_f(float v) {
    v = fminf(fmaxf(v, -15.0f), 15.0f);
    const float e = __expf(-2.0f * v);
    return (1.0f - e) / (1.0f + e);
}

// Persistent LSTM, 1 WG/CU, plain launch (grid == 256 == #CUs -> co-resident).
// WG w: rw=w>>3 owns hidden units 16rw..16rw+15 (64 gate rows) + out-features
// 4rw..4rw+3; bw=w&7 owns batches 8bw..8bw+7.
// Gate-GEMM thread split (DEDUPED, no spill): q=t>>4 -> K-slice [40q,40q+40),
// r4=t&15 -> rows 4r4..4r4+3, each thread covers all 8 batches.
// Weights: wreg[4][10] f32x4 = 160 VGPRs/thread, exactly the per-thread share.
// h crosses XCDs via sc0|sc1 loads/stores (L3 coherence point); grid barrier is
// fence-free monotonic counters -> per-XCD L2 (x, Wout) never invalidated.
__global__ __launch_bounds__(NTHR, 1)
void lstm_persist(const float* __restrict__ x,     // [B,S,F]
                  const float* __restrict__ Wih,   // [4H,F]
                  const float* __restrict__ Whh,   // [4H,H]
                  const float* __restrict__ bih,   // [4H]
                  const float* __restrict__ bhh,   // [4H]
                  const float* __restrict__ Wout,  // [F,H]
                  const float* __restrict__ bout,  // [F]
                  float* __restrict__ out,         // [B,S,F]
                  float* __restrict__ ws)          // [counters 4KB][2][B][H] h ring
{
    const int w = blockIdx.x, t = threadIdx.x;
    const int bw = w & 7, rw = w >> 3;

    const int q  = t >> 4;        // K-slice index [0,16)
    const int r4 = t & 15;        // row-quad index [0,16)
    const int k0 = 40 * q;

    // out-projection decomposition (4 feats x 8 batches x 8 K-slices of 64)
    const int out_fi  = (t >> 1) & 3;
    const int out_bb  = (t >> 3) & 7;
    const int out_ksl = ((t >> 6) << 1) | (t & 1);

    __shared__ float hx[8][HXS];       // staged [h(512) | x(128)] per local batch
    __shared__ float part[16 * PQS];   // gate partials: part[q*PQS + row*9 + batch]
    __shared__ float opart[4][8][9];   // out partials  [fi][batch][ksl(+pad)]
    __shared__ float gb[64];           // gate biases
    __shared__ float cst[16][9];       // c state [unit][batch(+pad)]
    __shared__ float bo[4];            // out biases

    // ---- one-time weight preload into registers: 4 rows x 10 quads (K=40) ----
    f32x4 wreg[4][10];
#pragma unroll
    for (int i = 0; i < 4; ++i) {
        const int r = 4 * r4 + i;                          // row in WG [0,64)
        const int G = (r >> 4) * Hn + rw * 16 + (r & 15);  // global gate row
#pragma unroll
        for (int j = 0; j < 10; ++j) {
            const int kk = k0 + 4 * j;
            if (kk < Hn) wreg[i][j] = *(const f32x4*)(Whh + (size_t)G * Hn + kk);
            else         wreg[i][j] = *(const f32x4*)(Wih + (size_t)G * Fn + (kk - Hn));
        }
    }

    if (t < 64) {
        const int G = (t >> 4) * Hn + rw * 16 + (t & 15);
        gb[t] = bih[G] + bhh[G];
    }
    if (t < 4) bo[t] = bout[rw * 4 + t];
    if (t < 128) cst[t >> 3][t & 7] = 0.0f;

    unsigned* const bar = (unsigned*)ws;  // root @0, group g @ 32*(g+1); memset by host
    float* const ring = ws + RING0;

    // ---- zero h_{-1} (ring slot 1): each WG zeroes exactly its owned cells ----
    if (t < 128) {
        const int ul = t & 15, bb = (t >> 4) & 7;
        float* hdst = ring + (size_t)(Bn * Hn) +
                      (size_t)(8 * bw + bb) * Hn + (16 * rw + ul);
        const float z = 0.0f;
        asm volatile("global_store_dword %0, %1, off sc0 sc1"
                     :: "v"(hdst), "v"(z) : "memory");
    }
    asm volatile("s_waitcnt vmcnt(0)" ::: "memory");
    __syncthreads();
    // ---- grid barrier, generation 1 ----
    if (t == 0) {
        unsigned* gcnt = bar + 32 * ((w >> 4) + 1);
        const unsigned old = atomicAdd(gcnt, 1u);
        if (old == 15u) atomicAdd(bar, 1u);
        int guard = 0;
        while (__hip_atomic_load(bar, __ATOMIC_RELAXED,
                                 __HIP_MEMORY_SCOPE_AGENT) < 16u) {
            __builtin_amdgcn_s_sleep(1);
            if (++guard > 100000) break;
        }
    }
    __syncthreads();

    for (int k = 0; k <= Sn; ++k) {
        // ---- stage h_{k-1} (ring slot (k&1)^1) for OUR 8 batches, sc0|sc1 ----
        const int slot = (k & 1) ^ 1;
        const float* hsrc = ring + (size_t)slot * (Bn * Hn) + (size_t)bw * 8 * Hn;
        f32x4 v0, v1, v2, v3;
        {
            const float* p0 = hsrc + 4 * t;
            const float* p1 = p0 + 1024;
            const float* p2 = p0 + 2048;
            const float* p3 = p0 + 3072;
            asm volatile(
                "global_load_dwordx4 %0, %4, off sc0 sc1\n\t"
                "global_load_dwordx4 %1, %5, off sc0 sc1\n\t"
                "global_load_dwordx4 %2, %6, off sc0 sc1\n\t"
                "global_load_dwordx4 %3, %7, off sc0 sc1\n\t"
                "s_waitcnt vmcnt(0)"
                : "=&v"(v0), "=&v"(v1), "=&v"(v2), "=&v"(v3)
                : "v"(p0), "v"(p1), "v"(p2), "v"(p3));
        }
        {
            int fi = t;
            *(f32x4*)&hx[fi >> 7][(fi & 127) * 4] = v0;
            fi = t + 256;
            *(f32x4*)&hx[fi >> 7][(fi & 127) * 4] = v1;
            fi = t + 512;
            *(f32x4*)&hx[fi >> 7][(fi & 127) * 4] = v2;
            fi = t + 768;
            *(f32x4*)&hx[fi >> 7][(fi & 127) * 4] = v3;
        }
        if (k < Sn) {  // stage x[:,k,:] for our 8 batches (plain cached loads)
            const int bb = t >> 5, f4 = (t & 31) * 4;
            const f32x4 v = *(const f32x4*)(x + (size_t)(8 * bw + bb) * Sn * Fn +
                                            (size_t)k * Fn + f4);
            *(f32x4*)&hx[bb][Hn + f4] = v;
        }
        __syncthreads();

        // ---- gate GEMM: acc[4 rows][8 batches] over K-slice [k0,k0+40) ----
        if (k < Sn) {
            float acc[4][8];
#pragma unroll
            for (int i = 0; i < 4; ++i)
#pragma unroll
                for (int ib = 0; ib < 8; ++ib) acc[i][ib] = 0.0f;
#pragma unroll
            for (int j = 0; j < 10; ++j) {
                f32x4 hv[4];
#pragma unroll
                for (int ib = 0; ib < 4; ++ib)
                    hv[ib] = *(const f32x4*)&hx[ib][k0 + 4 * j];
#pragma unroll
                for (int i = 0; i < 4; ++i)
#pragma unroll
                    for (int ib = 0; ib < 4; ++ib)
                        acc[i][ib] += wreg[i][j].x * hv[ib].x + wreg[i][j].y * hv[ib].y +
                                      wreg[i][j].z * hv[ib].z + wreg[i][j].w * hv[ib].w;
#pragma unroll
                for (int ib = 0; ib < 4; ++ib)
                    hv[ib] = *(const f32x4*)&hx[4 + ib][k0 + 4 * j];
#pragma unroll
                for (int i = 0; i < 4; ++i)
#pragma unroll
                    for (int ib = 0; ib < 4; ++ib)
                        acc[i][4 + ib] += wreg[i][j].x * hv[ib].x + wreg[i][j].y * hv[ib].y +
                                          wreg[i][j].z * hv[ib].z + wreg[i][j].w * hv[ib].w;
            }
#pragma unroll
            for (int i = 0; i < 4; ++i)
#pragma unroll
                for (int ib = 0; ib < 8; ++ib)
                    part[q * PQS + (4 * r4 + i) * 9 + ib] = acc[i][ib];
        }

        // ---- pipelined out-projection for step k-1 (uses staged h_{k-1}) ----
        if (k >= 1) {
            const float* wo = Wout + (size_t)(rw * 4 + out_fi) * Hn + out_ksl * 64;
            const float* hrow = &hx[out_bb][out_ksl * 64];
            float oa = 0.0f;
#pragma unroll
            for (int jj = 0; jj < 16; ++jj) {
                const f32x4 wv = *(const f32x4*)(wo + 4 * jj);
                const f32x4 hv = *(const f32x4*)(hrow + 4 * jj);
                oa += wv.x * hv.x + wv.y * hv.y + wv.z * hv.z + wv.w * hv.w;
            }
            opart[out_fi][out_bb][out_ksl] = oa;
        }
        __syncthreads();

        // ---- cell update (t<128) + out finalize (t in [128,160)) ----
        if (k < Sn && t < 128) {
            const int ul = t & 15, bb = (t >> 4) & 7;
            float g4[4];
#pragma unroll
            for (int gate = 0; gate < 4; ++gate) {
                const int r = gate * 16 + ul;
                float s = gb[r];
#pragma unroll
                for (int qq = 0; qq < 16; ++qq) s += part[qq * PQS + r * 9 + bb];
                g4[gate] = s;
            }
            const float ig = sigmoid_f(g4[0]);
            const float fg = sigmoid_f(g4[1]);
            const float gg = tanh_f(g4[2]);
            const float og = sigmoid_f(g4[3]);
            const float cn = fg * cst[ul][bb] + ig * gg;
            cst[ul][bb] = cn;
            const float hn = og * tanh_f(cn);
            float* hdst = ring + (size_t)(k & 1) * (Bn * Hn) +
                          (size_t)(8 * bw + bb) * Hn + (16 * rw + ul);
            // write-through to the L3 coherence point
            asm volatile("global_store_dword %0, %1, off sc0 sc1"
                         :: "v"(hdst), "v"(hn) : "memory");
        } else if (k >= 1 && t >= 128 && t < 160) {
            const int fi = (t - 128) >> 3, bb = (t - 128) & 7;
            float s = bo[fi];
#pragma unroll
            for (int qq = 0; qq < 8; ++qq) s += opart[fi][bb][qq];
            out[(size_t)(8 * bw + bb) * Sn * Fn + (size_t)(k - 1) * Fn + rw * 4 + fi] = s;
        }

        // ---- fence-free 2-level grid barrier (generation counters) ----
        if (k < Sn) {
            asm volatile("s_waitcnt vmcnt(0)" ::: "memory");  // h stores are in L3
            __syncthreads();
            if (t == 0) {
                const unsigned gen = (unsigned)(k + 2);  // gen 1 was the init barrier
                unsigned* gcnt = bar + 32 * ((w >> 4) + 1);
                const unsigned old = atomicAdd(gcnt, 1u);
                if (old == 16u * gen - 1u) atomicAdd(bar, 1u);
                const unsigned target = 16u * gen;
                int guard = 0;
                while (__hip_atomic_load(bar, __ATOMIC_RELAXED,
                                         __HIP_MEMORY_SCOPE_AGENT) < target) {
                    __builtin_amdgcn_s_sleep(1);
                    if (++guard > 100000) break;  // fail loud (wrong data), never hang
                }
            }
            __syncthreads();
        }
    }
}

extern "C" void kernel_launch(void* const* d_in, const int* in_sizes, int n_in,
                              void* d_out, int out_size, void* d_ws, size_t ws_size,
                              hipStream_t stream) {
    (void)in_sizes; (void)n_in; (void)out_size; (void)ws_size;
    const float* x    = (const float*)d_in[0];
    const float* Wih  = (const float*)d_in[1];
    const float* Whh  = (const float*)d_in[2];
    const float* bih  = (const float*)d_in[3];
    const float* bhh  = (const float*)d_in[4];
    const float* Wout = (const float*)d_in[5];
    const float* bout = (const float*)d_in[6];
    float* out = (float*)d_out;
    float* wsp = (float*)d_ws;  // [4 KB counters][256 KB h ring]

    hipMemsetAsync(d_ws, 0, 4096, stream);  // barrier counters only

    lstm_persist<<<dim3(NWG), dim3(NTHR), 0, stream>>>(
        x, Wih, Whh, bih, bhh, Wout, bout, out, wsp);
}

// Round 6
// 8995.788 us; speedup vs baseline: 1.2856x; 1.2856x over previous
//
#include <hip/hip_runtime.h>

typedef float f32x4 __attribute__((ext_vector_type(4)));

namespace {
constexpr int Bn = 64, Sn = 512, Fn = 128, Hn = 512;
constexpr int NWG = 256, NTHR = 512;
constexpr int HXS = 644;    // hx row stride (dwords), 16B-aligned
constexpr int PQS = 581;    // part q-plane stride (dwords): 581%32=5 -> spread banks
constexpr int RING0 = 1024; // ring base offset in floats (first 4 KB = barrier counters)
}

__device__ __forceinline__ float sigmoid_f(float v) {
    return 1.0f / (1.0f + __expf(-v));
}
__device__ __forceinline__ float tanh_f(float v) {
    v = fminf(fmaxf(v, -15.0f), 15.0f);
    const float e = __expf(-2.0f * v);
    return (1.0f - e) / (1.0f + e);
}

// Persistent LSTM, 1 WG/CU (LDS 97KB forces it), plain launch, 256 WGs co-resident.
// WG w: rw=w>>3 owns hidden units 16rw..16rw+15 (64 gate rows) + out-features
// 4rw..4rw+3; bw=w&7 owns batches 8bw..8bw+7.
// Gate-GEMM split (512 thr, NO spill): q=t&31 -> K-slice [20q,20q+20), r4=t>>5 ->
// rows 4r4..4r4+3, all 8 batches. Weights wreg[4][5] f32x4 = 80 VGPRs/thread.
// h crosses XCDs via sc0|sc1 loads/stores (L3 coherence point); grid barrier is
// fence-free monotonic counters -> per-XCD L2 (x, Wout) never invalidated.
__global__ __launch_bounds__(NTHR, 2)
void lstm_persist(const float* __restrict__ x,     // [B,S,F]
                  const float* __restrict__ Wih,   // [4H,F]
                  const float* __restrict__ Whh,   // [4H,H]
                  const float* __restrict__ bih,   // [4H]
                  const float* __restrict__ bhh,   // [4H]
                  const float* __restrict__ Wout,  // [F,H]
                  const float* __restrict__ bout,  // [F]
                  float* __restrict__ out,         // [B,S,F]
                  float* __restrict__ ws)          // [counters 4KB][2][B][H] h ring
{
    const int w = blockIdx.x, t = threadIdx.x;
    const int bw = w & 7, rw = w >> 3;

    const int q  = t & 31;        // K-slice index [0,32)
    const int r4 = t >> 5;        // row-quad index [0,16)
    const int k0 = 20 * q;

    // out-projection decomposition (threads 0..255: 4 feats x 8 batches x 8 K-slices)
    const int out_fi  = (t >> 1) & 3;
    const int out_bb  = (t >> 3) & 7;
    const int out_ksl = ((t >> 6) << 1) | (t & 1);

    __shared__ float hx[8][HXS];       // staged [h(512) | x(128)] per local batch
    __shared__ float part[32 * PQS];   // gate partials: part[q*PQS + row*9 + batch]
    __shared__ float opart[4][8][9];   // out partials  [fi][batch][ksl(+pad)]
    __shared__ float gb[64];           // gate biases
    __shared__ float cst[16][9];       // c state [unit][batch(+pad)]
    __shared__ float bo[4];            // out biases

    // ---- one-time weight preload into registers: 4 rows x 5 quads (K=20) ----
    f32x4 wreg[4][5];
#pragma unroll
    for (int i = 0; i < 4; ++i) {
        const int r = 4 * r4 + i;                          // row in WG [0,64)
        const int G = (r >> 4) * Hn + rw * 16 + (r & 15);  // global gate row
#pragma unroll
        for (int j = 0; j < 5; ++j) {
            const int kk = k0 + 4 * j;
            if (kk < Hn) wreg[i][j] = *(const f32x4*)(Whh + (size_t)G * Hn + kk);
            else         wreg[i][j] = *(const f32x4*)(Wih + (size_t)G * Fn + (kk - Hn));
        }
    }

    if (t < 64) {
        const int G = (t >> 4) * Hn + rw * 16 + (t & 15);
        gb[t] = bih[G] + bhh[G];
    }
    if (t < 4) bo[t] = bout[rw * 4 + t];
    if (t < 128) cst[t >> 3][t & 7] = 0.0f;

    unsigned* const bar = (unsigned*)ws;  // root @0, group g @ 32*(g+1); memset by host
    float* const ring = ws + RING0;

    // ---- zero h_{-1} (ring slot 1): each WG zeroes exactly its owned cells ----
    if (t < 128) {
        const int ul = t & 15, bb = (t >> 4) & 7;
        float* hdst = ring + (size_t)(Bn * Hn) +
                      (size_t)(8 * bw + bb) * Hn + (16 * rw + ul);
        const float z = 0.0f;
        asm volatile("global_store_dword %0, %1, off sc0 sc1"
                     :: "v"(hdst), "v"(z) : "memory");
    }
    asm volatile("s_waitcnt vmcnt(0)" ::: "memory");
    __syncthreads();
    // ---- grid barrier, generation 1 ----
    if (t == 0) {
        unsigned* gcnt = bar + 32 * ((w >> 4) + 1);
        const unsigned old = atomicAdd(gcnt, 1u);
        if (old == 15u) atomicAdd(bar, 1u);
        int guard = 0;
        while (__hip_atomic_load(bar, __ATOMIC_RELAXED,
                                 __HIP_MEMORY_SCOPE_AGENT) < 16u) {
            __builtin_amdgcn_s_sleep(1);
            if (++guard > 100000) break;
        }
    }
    __syncthreads();

    for (int k = 0; k <= Sn; ++k) {
        // ---- stage h_{k-1} (ring slot (k&1)^1) for OUR 8 batches, sc0|sc1 ----
        const int slot = (k & 1) ^ 1;
        const float* hsrc = ring + (size_t)slot * (Bn * Hn) + (size_t)bw * 8 * Hn;
        f32x4 v0, v1;
        {
            const float* p0 = hsrc + 4 * t;
            const float* p1 = p0 + 2048;
            asm volatile(
                "global_load_dwordx4 %0, %2, off sc0 sc1\n\t"
                "global_load_dwordx4 %1, %3, off sc0 sc1\n\t"
                "s_waitcnt vmcnt(0)"
                : "=&v"(v0), "=&v"(v1)
                : "v"(p0), "v"(p1));
        }
        {
            int fi = t;                                   // b128 index in [0,1024)
            *(f32x4*)&hx[fi >> 7][(fi & 127) * 4] = v0;
            fi = t + 512;
            *(f32x4*)&hx[fi >> 7][(fi & 127) * 4] = v1;
        }
        if (k < Sn && t < 256) {  // stage x[:,k,:] for our 8 batches (cached loads)
            const int bb = t >> 5, f4 = (t & 31) * 4;
            const f32x4 v = *(const f32x4*)(x + (size_t)(8 * bw + bb) * Sn * Fn +
                                            (size_t)k * Fn + f4);
            *(f32x4*)&hx[bb][Hn + f4] = v;
        }
        __syncthreads();

        // ---- gate GEMM: acc[4 rows][8 batches] over K-slice [k0,k0+20) ----
        if (k < Sn) {
            float acc[4][8];
#pragma unroll
            for (int i = 0; i < 4; ++i)
#pragma unroll
                for (int ib = 0; ib < 8; ++ib) acc[i][ib] = 0.0f;
#pragma unroll
            for (int j = 0; j < 5; ++j) {
                f32x4 hv[4];
#pragma unroll
                for (int ib = 0; ib < 4; ++ib)
                    hv[ib] = *(const f32x4*)&hx[ib][k0 + 4 * j];
#pragma unroll
                for (int i = 0; i < 4; ++i)
#pragma unroll
                    for (int ib = 0; ib < 4; ++ib)
                        acc[i][ib] += wreg[i][j].x * hv[ib].x + wreg[i][j].y * hv[ib].y +
                                      wreg[i][j].z * hv[ib].z + wreg[i][j].w * hv[ib].w;
#pragma unroll
                for (int ib = 0; ib < 4; ++ib)
                    hv[ib] = *(const f32x4*)&hx[4 + ib][k0 + 4 * j];
#pragma unroll
                for (int i = 0; i < 4; ++i)
#pragma unroll
                    for (int ib = 0; ib < 4; ++ib)
                        acc[i][4 + ib] += wreg[i][j].x * hv[ib].x + wreg[i][j].y * hv[ib].y +
                                          wreg[i][j].z * hv[ib].z + wreg[i][j].w * hv[ib].w;
            }
#pragma unroll
            for (int i = 0; i < 4; ++i)
#pragma unroll
                for (int ib = 0; ib < 8; ++ib)
                    part[q * PQS + (4 * r4 + i) * 9 + ib] = acc[i][ib];
        }

        // ---- pipelined out-projection for step k-1 (uses staged h_{k-1}) ----
        if (k >= 1 && t < 256) {
            const float* wo = Wout + (size_t)(rw * 4 + out_fi) * Hn + out_ksl * 64;
            const float* hrow = &hx[out_bb][out_ksl * 64];
            float oa = 0.0f;
#pragma unroll
            for (int jj = 0; jj < 16; ++jj) {
                const f32x4 wv = *(const f32x4*)(wo + 4 * jj);
                const f32x4 hv = *(const f32x4*)(hrow + 4 * jj);
                oa += wv.x * hv.x + wv.y * hv.y + wv.z * hv.z + wv.w * hv.w;
            }
            opart[out_fi][out_bb][out_ksl] = oa;
        }
        __syncthreads();

        // ---- cell update (t<128) + out finalize (t in [128,160)) ----
        if (k < Sn && t < 128) {
            const int ul = t & 15, bb = (t >> 4) & 7;
            float g4[4];
#pragma unroll
            for (int gate = 0; gate < 4; ++gate) {
                const int r = gate * 16 + ul;
                float s = gb[r];
#pragma unroll
                for (int qq = 0; qq < 32; ++qq) s += part[qq * PQS + r * 9 + bb];
                g4[gate] = s;
            }
            const float ig = sigmoid_f(g4[0]);
            const float fg = sigmoid_f(g4[1]);
            const float gg = tanh_f(g4[2]);
            const float og = sigmoid_f(g4[3]);
            const float cn = fg * cst[ul][bb] + ig * gg;
            cst[ul][bb] = cn;
            const float hn = og * tanh_f(cn);
            float* hdst = ring + (size_t)(k & 1) * (Bn * Hn) +
                          (size_t)(8 * bw + bb) * Hn + (16 * rw + ul);
            // write-through to the L3 coherence point
            asm volatile("global_store_dword %0, %1, off sc0 sc1"
                         :: "v"(hdst), "v"(hn) : "memory");
        } else if (k >= 1 && t >= 128 && t < 160) {
            const int fi = (t - 128) >> 3, bb = (t - 128) & 7;
            float s = bo[fi];
#pragma unroll
            for (int qq = 0; qq < 8; ++qq) s += opart[fi][bb][qq];
            out[(size_t)(8 * bw + bb) * Sn * Fn + (size_t)(k - 1) * Fn + rw * 4 + fi] = s;
        }

        // ---- fence-free 2-level grid barrier (generation counters) ----
        if (k < Sn) {
            asm volatile("s_waitcnt vmcnt(0)" ::: "memory");  // h stores are in L3
            __syncthreads();
            if (t == 0) {
                const unsigned gen = (unsigned)(k + 2);  // gen 1 was the init barrier
                unsigned* gcnt = bar + 32 * ((w >> 4) + 1);
                const unsigned old = atomicAdd(gcnt, 1u);
                if (old == 16u * gen - 1u) atomicAdd(bar, 1u);
                const unsigned target = 16u * gen;
                int guard = 0;
                while (__hip_atomic_load(bar, __ATOMIC_RELAXED,
                                         __HIP_MEMORY_SCOPE_AGENT) < target) {
                    __builtin_amdgcn_s_sleep(1);
                    if (++guard > 100000) break;  // fail loud (wrong data), never hang
                }
            }
            __syncthreads();
        }
    }
}

extern "C" void kernel_launch(void* const* d_in, const int* in_sizes, int n_in,
                              void* d_out, int out_size, void* d_ws, size_t ws_size,
                              hipStream_t stream) {
    (void)in_sizes; (void)n_in; (void)out_size; (void)ws_size;
    const float* x    = (const float*)d_in[0];
    const float* Wih  = (const float*)d_in[1];
    const float* Whh  = (const float*)d_in[2];
    const float* bih  = (const float*)d_in[3];
    const float* bhh  = (const float*)d_in[4];
    const float* Wout = (const float*)d_in[5];
    const float* bout = (const float*)d_in[6];
    float* out = (float*)d_out;
    float* wsp = (float*)d_ws;  // [4 KB counters][256 KB h ring]

    hipMemsetAsync(d_ws, 0, 4096, stream);  // barrier counters only

    lstm_persist<<<dim3(NWG), dim3(NTHR), 0, stream>>>(
        x, Wih, Whh, bih, bhh, Wout, bout, out, wsp);
}